// Round 6
// baseline (314.700 us; speedup 1.0000x reference)
//
#include <hip/hip_runtime.h>
#include <hip/hip_bf16.h>

// SoftmaxPermutationMatrix: out[b,x,y] = softmax_y(cos(xn,yn)/0.2) * mx[b,x] * my[b,y]
// Two-pass recompute scheme (scores bounded in [-5,5] => no max needed).
// R6: MEASUREMENT ROUND. Source = R4 exactly (pass1 reverted from R5's
//     regressed prefetch variant). pass1 is launched 4x (idempotent, writes
//     identical values) => total = T_R4 + 3*pass1_dur. This extracts the
//     pass1/pass2 split that rocprof's fillBuffer-flooded top-5 hides.

typedef __attribute__((ext_vector_type(8))) short short8;
typedef __attribute__((ext_vector_type(4))) float float4v;

constexpr int B = 2, NX = 8192, NY = 8192, DD = 128;
constexpr int BM = 128, BN = 128;
constexpr int NSPLIT = 8;
constexpr int YCHUNK = NY / NSPLIT;   // 1024
constexpr int ROWB = 256;             // bytes per LDS row (128 bf16, linear)
constexpr float TAU_INV = 5.0f;

__device__ __forceinline__ void gload16(const void* g, void* l) {
    __builtin_amdgcn_global_load_lds(
        (const __attribute__((address_space(1))) void*)g,
        (__attribute__((address_space(3))) void*)l, 16, 0, 0);
}

// Stage 128 rows x 256B from gsrc into lds (linear), content swizzled so that
// LDS(row, cb) = G(row, cb ^ ((row&7)<<4)). Each wave stages 32 rows.
__device__ __forceinline__ void stage_tile(const char* gsrc, char* lds, int wid, int lane) {
    const int srow = wid * 32;
    const int lr4 = lane >> 4;
    const int lcb = (lane & 15) * 16;
#pragma unroll
    for (int i = 0; i < 8; ++i) {
        int row = srow + i * 4 + lr4;
        int scb = lcb ^ ((row & 7) << 4);
        gload16(gsrc + (size_t)row * ROWB + scb, lds + (srow + i * 4) * ROWB);
    }
}

// ---------------- L2 normalize + cast to bf16 (one wave per 128-elem row) ----------------
__global__ __launch_bounds__(256) void l2norm_kernel(const float* __restrict__ in,
                                                     __hip_bfloat16* __restrict__ out,
                                                     int rows) {
    int wid = threadIdx.x >> 6, lane = threadIdx.x & 63;
    int row = blockIdx.x * 4 + wid;
    if (row >= rows) return;
    float2 v = ((const float2*)(in + (size_t)row * DD))[lane];
    float ss = v.x * v.x + v.y * v.y;
#pragma unroll
    for (int off = 32; off >= 1; off >>= 1) ss += __shfl_xor(ss, off);
    float inv = 1.0f / fmaxf(sqrtf(ss), 1e-12f);
    __hip_bfloat162 o;
    o.x = __float2bfloat16(v.x * inv);
    o.y = __float2bfloat16(v.y * inv);
    ((__hip_bfloat162*)(out + (size_t)row * DD))[lane] = o;
}

// ---------------- pass 1: per-x-row sum of exp(score) over a Ny chunk ----------------
__global__ __launch_bounds__(256) void pass1_kernel(const __hip_bfloat16* __restrict__ Xn,
                                                    const __hip_bfloat16* __restrict__ Yn,
                                                    float* __restrict__ partial) {
    __shared__ __hip_bfloat16 Xs[BM][DD];
    __shared__ __hip_bfloat16 Ys[BN][DD];
    const int split = blockIdx.x, xt = blockIdx.y, b = blockIdx.z;
    const int t = threadIdx.x;
    const int lane = t & 63, wid = t >> 6;
    const int wm = wid >> 1, wn = wid & 1;        // 2x2 waves, each 64x64 output
    const int lrow = lane & 15, lhi = lane >> 4;

    // stage X tile once (K = full D = 128, no K loop)
    stage_tile((const char*)(Xn + (size_t)(b * NX + xt * BM) * DD), (char*)&Xs[0][0], wid, lane);

    float run[4][4];
#pragma unroll
    for (int m = 0; m < 4; ++m)
#pragma unroll
        for (int r = 0; r < 4; ++r) run[m][r] = 0.f;

    for (int tile = 0; tile < YCHUNK / BN; ++tile) {
        __syncthreads();   // prev reads done (and, at tile 0, nothing pending)
        stage_tile((const char*)(Yn + (size_t)(b * NY + split * YCHUNK + tile * BN) * DD),
                   (char*)&Ys[0][0], wid, lane);
        __syncthreads();   // staging (vmcnt) drained

        float4v acc[4][4];
#pragma unroll
        for (int m = 0; m < 4; ++m)
#pragma unroll
            for (int n = 0; n < 4; ++n) acc[m][n] = (float4v)(0.f);
#pragma unroll
        for (int kk = 0; kk < 4; ++kk) {
            const int cb = (kk * 64 + lhi * 16) ^ ((lrow & 7) << 4);
            short8 a[4], bb[4];
#pragma unroll
            for (int m = 0; m < 4; ++m)
                a[m] = *(const short8*)((const char*)Xs + (size_t)(wm * 64 + m * 16 + lrow) * ROWB + cb);
#pragma unroll
            for (int n = 0; n < 4; ++n)
                bb[n] = *(const short8*)((const char*)Ys + (size_t)(wn * 64 + n * 16 + lrow) * ROWB + cb);
#pragma unroll
            for (int m = 0; m < 4; ++m)
#pragma unroll
                for (int n = 0; n < 4; ++n)
                    acc[m][n] = __builtin_amdgcn_mfma_f32_16x16x32_bf16(a[m], bb[n], acc[m][n], 0, 0, 0);
        }
#pragma unroll
        for (int m = 0; m < 4; ++m)
#pragma unroll
            for (int r = 0; r < 4; ++r) {
                float s = 0.f;
#pragma unroll
                for (int n = 0; n < 4; ++n) s += __expf(acc[m][n][r] * TAU_INV);
                run[m][r] += s;
            }
    }

    // butterfly across the 16 lanes sharing the same x (low 4 lane bits)
#pragma unroll
    for (int m = 0; m < 4; ++m)
#pragma unroll
        for (int r = 0; r < 4; ++r) {
            float v = run[m][r];
            v += __shfl_xor(v, 1);
            v += __shfl_xor(v, 2);
            v += __shfl_xor(v, 4);
            v += __shfl_xor(v, 8);
            run[m][r] = v;
        }

    __syncthreads();
    float* lred = (float*)Ys;  // reuse LDS: [2][128]
    if (lrow == 0) {
#pragma unroll
        for (int m = 0; m < 4; ++m)
#pragma unroll
            for (int r = 0; r < 4; ++r) {
                int xl = wm * 64 + m * 16 + lhi * 4 + r;
                lred[wn * BM + xl] = run[m][r];
            }
    }
    __syncthreads();
    if (t < BM) {
        float tot = lred[t] + lred[BM + t];
        partial[(size_t)split * (B * NX) + (size_t)b * NX + xt * BM + t] = tot;
    }
}

// ---------------- combine partial sums -> rowscale = mask_x / sum ----------------
__global__ void combine_kernel(const float* __restrict__ partial,
                               const float* __restrict__ maskx,
                               float* __restrict__ rowscale) {
    int idx = blockIdx.x * 256 + threadIdx.x;
    if (idx >= B * NX) return;
    float s = 0.f;
#pragma unroll
    for (int i = 0; i < NSPLIT; ++i) s += partial[(size_t)i * (B * NX) + idx];
    rowscale[idx] = maskx[idx] / s;
}

// ---------------- pass 2: LDS-staged (gload_lds+swz), transposed MFMA, float4 stores ----
__global__ __launch_bounds__(256) void pass2_kernel(const __hip_bfloat16* __restrict__ Xn,
                                                    const __hip_bfloat16* __restrict__ Yn,
                                                    const float* __restrict__ rowscale,
                                                    const float* __restrict__ masky,
                                                    float* __restrict__ out) {
    __shared__ __hip_bfloat16 Xs[BM][DD];
    __shared__ __hip_bfloat16 Ys[BN][DD];
    const int yt = blockIdx.x, xt = blockIdx.y, b = blockIdx.z;
    const int t = threadIdx.x;
    const int lane = t & 63, wid = t >> 6;
    const int wy = wid >> 1, wx = wid & 1;        // 2x2 waves, each 64y x 64x
    const int lrow = lane & 15, lhi = lane >> 4;

    stage_tile((const char*)(Xn + (size_t)(b * NX + xt * BM) * DD), (char*)&Xs[0][0], wid, lane);
    stage_tile((const char*)(Yn + (size_t)(b * NY + yt * BN) * DD), (char*)&Ys[0][0], wid, lane);
    __syncthreads();

    float4v acc[4][4];  // [n = y frag][m = x frag]
#pragma unroll
    for (int n = 0; n < 4; ++n)
#pragma unroll
        for (int m = 0; m < 4; ++m) acc[n][m] = (float4v)(0.f);

#pragma unroll
    for (int kk = 0; kk < 4; ++kk) {
        const int cb = (kk * 64 + lhi * 16) ^ ((lrow & 7) << 4);
        short8 a[4], bb[4];
#pragma unroll
        for (int n = 0; n < 4; ++n)
            a[n] = *(const short8*)((const char*)Ys + (size_t)(wy * 64 + n * 16 + lrow) * ROWB + cb);
#pragma unroll
        for (int m = 0; m < 4; ++m)
            bb[m] = *(const short8*)((const char*)Xs + (size_t)(wx * 64 + m * 16 + lrow) * ROWB + cb);
#pragma unroll
        for (int n = 0; n < 4; ++n)
#pragma unroll
            for (int m = 0; m < 4; ++m)
                acc[n][m] = __builtin_amdgcn_mfma_f32_16x16x32_bf16(a[n], bb[m], acc[n][m], 0, 0, 0);
    }

    const int ybase = yt * BN + wy * 64;
    const int xbase = xt * BM + wx * 64;

    float rs[4];
#pragma unroll
    for (int m = 0; m < 4; ++m)
        rs[m] = rowscale[(size_t)b * NX + xbase + m * 16 + lrow];
    float4v my4[4];
#pragma unroll
    for (int n = 0; n < 4; ++n)
        my4[n] = *(const float4v*)(masky + (size_t)b * NY + ybase + n * 16 + lhi * 4);

#pragma unroll
    for (int m = 0; m < 4; ++m) {
        const int x = xbase + m * 16 + lrow;
        float* orow = out + ((size_t)b * NX + x) * NY;
#pragma unroll
        for (int n = 0; n < 4; ++n) {
            float4v o;
#pragma unroll
            for (int r = 0; r < 4; ++r)
                o[r] = __expf(acc[n][m][r] * TAU_INV) * rs[m] * my4[n][r];
            *(float4v*)(orow + ybase + n * 16 + lhi * 4) = o;  // plain store: L2 write-combining
        }
    }
}

extern "C" void kernel_launch(void* const* d_in, const int* in_sizes, int n_in,
                              void* d_out, int out_size, void* d_ws, size_t ws_size,
                              hipStream_t stream) {
    const float* feat_x = (const float*)d_in[0];
    const float* feat_y = (const float*)d_in[1];
    const float* maskx  = (const float*)d_in[2];
    const float* masky  = (const float*)d_in[3];
    float* out = (float*)d_out;

    char* ws = (char*)d_ws;
    __hip_bfloat16* Xn = (__hip_bfloat16*)ws;                                   // 4 MB
    __hip_bfloat16* Yn = (__hip_bfloat16*)(ws + (size_t)B * NX * DD * 2);       // 4 MB
    float* partial  = (float*)(ws + (size_t)B * (NX + NY) * DD * 2);            // 512 KB
    float* rowscale = partial + (size_t)NSPLIT * B * NX;                        // 64 KB

    l2norm_kernel<<<B * NX / 4, 256, 0, stream>>>(feat_x, Xn, B * NX);
    l2norm_kernel<<<B * NY / 4, 256, 0, stream>>>(feat_y, Yn, B * NY);
    // MEASUREMENT: pass1 launched 4x (idempotent). total = T_R4 + 3*pass1_dur.
    pass1_kernel<<<dim3(NSPLIT, NX / BM, B), 256, 0, stream>>>(Xn, Yn, partial);
    pass1_kernel<<<dim3(NSPLIT, NX / BM, B), 256, 0, stream>>>(Xn, Yn, partial);
    pass1_kernel<<<dim3(NSPLIT, NX / BM, B), 256, 0, stream>>>(Xn, Yn, partial);
    pass1_kernel<<<dim3(NSPLIT, NX / BM, B), 256, 0, stream>>>(Xn, Yn, partial);
    combine_kernel<<<(B * NX + 255) / 256, 256, 0, stream>>>(partial, maskx, rowscale);
    pass2_kernel<<<dim3(NY / BN, NX / BM, B), 256, 0, stream>>>(Xn, Yn, rowscale, masky, out);
}

// Round 7
// 176.038 us; speedup vs baseline: 1.7877x; 1.7877x over previous
//
#include <hip/hip_runtime.h>
#include <hip/hip_bf16.h>

// SoftmaxPermutationMatrix: out[b,x,y] = softmax_y(cos(xn,yn)/0.2) * mx[b,x] * my[b,y]
// Two-pass recompute scheme (scores bounded in [-5,5] => no max needed).
// R7: pass2 epilogue now transposes through LDS (reusing the 64KB staging
//     buffer) so each wave store instruction writes 2 complete 512B output
//     row-segments (full 128B lines), replacing the 16-way 64B scatter.
//     Tests theory (b): 64B-segment stores under-utilize write BW.
//     pass1 = R4/R6 version (45.4us measured), launched once.

typedef __attribute__((ext_vector_type(8))) short short8;
typedef __attribute__((ext_vector_type(4))) float float4v;

constexpr int B = 2, NX = 8192, NY = 8192, DD = 128;
constexpr int BM = 128, BN = 128;
constexpr int NSPLIT = 8;
constexpr int YCHUNK = NY / NSPLIT;   // 1024
constexpr int ROWB = 256;             // bytes per LDS row (128 bf16, linear)
constexpr float TAU_INV = 5.0f;

__device__ __forceinline__ void gload16(const void* g, void* l) {
    __builtin_amdgcn_global_load_lds(
        (const __attribute__((address_space(1))) void*)g,
        (__attribute__((address_space(3))) void*)l, 16, 0, 0);
}

// Stage 128 rows x 256B from gsrc into lds (linear), content swizzled so that
// LDS(row, cb) = G(row, cb ^ ((row&7)<<4)). Each wave stages 32 rows.
__device__ __forceinline__ void stage_tile(const char* gsrc, char* lds, int wid, int lane) {
    const int srow = wid * 32;
    const int lr4 = lane >> 4;
    const int lcb = (lane & 15) * 16;
#pragma unroll
    for (int i = 0; i < 8; ++i) {
        int row = srow + i * 4 + lr4;
        int scb = lcb ^ ((row & 7) << 4);
        gload16(gsrc + (size_t)row * ROWB + scb, lds + (srow + i * 4) * ROWB);
    }
}

// ---------------- L2 normalize + cast to bf16 (one wave per 128-elem row) ----------------
__global__ __launch_bounds__(256) void l2norm_kernel(const float* __restrict__ in,
                                                     __hip_bfloat16* __restrict__ out,
                                                     int rows) {
    int wid = threadIdx.x >> 6, lane = threadIdx.x & 63;
    int row = blockIdx.x * 4 + wid;
    if (row >= rows) return;
    float2 v = ((const float2*)(in + (size_t)row * DD))[lane];
    float ss = v.x * v.x + v.y * v.y;
#pragma unroll
    for (int off = 32; off >= 1; off >>= 1) ss += __shfl_xor(ss, off);
    float inv = 1.0f / fmaxf(sqrtf(ss), 1e-12f);
    __hip_bfloat162 o;
    o.x = __float2bfloat16(v.x * inv);
    o.y = __float2bfloat16(v.y * inv);
    ((__hip_bfloat162*)(out + (size_t)row * DD))[lane] = o;
}

// ---------------- pass 1: per-x-row sum of exp(score) over a Ny chunk ----------------
__global__ __launch_bounds__(256) void pass1_kernel(const __hip_bfloat16* __restrict__ Xn,
                                                    const __hip_bfloat16* __restrict__ Yn,
                                                    float* __restrict__ partial) {
    __shared__ __hip_bfloat16 Xs[BM][DD];
    __shared__ __hip_bfloat16 Ys[BN][DD];
    const int split = blockIdx.x, xt = blockIdx.y, b = blockIdx.z;
    const int t = threadIdx.x;
    const int lane = t & 63, wid = t >> 6;
    const int wm = wid >> 1, wn = wid & 1;        // 2x2 waves, each 64x64 output
    const int lrow = lane & 15, lhi = lane >> 4;

    // stage X tile once (K = full D = 128, no K loop)
    stage_tile((const char*)(Xn + (size_t)(b * NX + xt * BM) * DD), (char*)&Xs[0][0], wid, lane);

    float run[4][4];
#pragma unroll
    for (int m = 0; m < 4; ++m)
#pragma unroll
        for (int r = 0; r < 4; ++r) run[m][r] = 0.f;

    for (int tile = 0; tile < YCHUNK / BN; ++tile) {
        __syncthreads();   // prev reads done (and, at tile 0, nothing pending)
        stage_tile((const char*)(Yn + (size_t)(b * NY + split * YCHUNK + tile * BN) * DD),
                   (char*)&Ys[0][0], wid, lane);
        __syncthreads();   // staging (vmcnt) drained

        float4v acc[4][4];
#pragma unroll
        for (int m = 0; m < 4; ++m)
#pragma unroll
            for (int n = 0; n < 4; ++n) acc[m][n] = (float4v)(0.f);
#pragma unroll
        for (int kk = 0; kk < 4; ++kk) {
            const int cb = (kk * 64 + lhi * 16) ^ ((lrow & 7) << 4);
            short8 a[4], bb[4];
#pragma unroll
            for (int m = 0; m < 4; ++m)
                a[m] = *(const short8*)((const char*)Xs + (size_t)(wm * 64 + m * 16 + lrow) * ROWB + cb);
#pragma unroll
            for (int n = 0; n < 4; ++n)
                bb[n] = *(const short8*)((const char*)Ys + (size_t)(wn * 64 + n * 16 + lrow) * ROWB + cb);
#pragma unroll
            for (int m = 0; m < 4; ++m)
#pragma unroll
                for (int n = 0; n < 4; ++n)
                    acc[m][n] = __builtin_amdgcn_mfma_f32_16x16x32_bf16(a[m], bb[n], acc[m][n], 0, 0, 0);
        }
#pragma unroll
        for (int m = 0; m < 4; ++m)
#pragma unroll
            for (int r = 0; r < 4; ++r) {
                float s = 0.f;
#pragma unroll
                for (int n = 0; n < 4; ++n) s += __expf(acc[m][n][r] * TAU_INV);
                run[m][r] += s;
            }
    }

    // butterfly across the 16 lanes sharing the same x (low 4 lane bits)
#pragma unroll
    for (int m = 0; m < 4; ++m)
#pragma unroll
        for (int r = 0; r < 4; ++r) {
            float v = run[m][r];
            v += __shfl_xor(v, 1);
            v += __shfl_xor(v, 2);
            v += __shfl_xor(v, 4);
            v += __shfl_xor(v, 8);
            run[m][r] = v;
        }

    __syncthreads();
    float* lred = (float*)Ys;  // reuse LDS: [2][128]
    if (lrow == 0) {
#pragma unroll
        for (int m = 0; m < 4; ++m)
#pragma unroll
            for (int r = 0; r < 4; ++r) {
                int xl = wm * 64 + m * 16 + lhi * 4 + r;
                lred[wn * BM + xl] = run[m][r];
            }
    }
    __syncthreads();
    if (t < BM) {
        float tot = lred[t] + lred[BM + t];
        partial[(size_t)split * (B * NX) + (size_t)b * NX + xt * BM + t] = tot;
    }
}

// ---------------- combine partial sums -> rowscale = mask_x / sum ----------------
__global__ void combine_kernel(const float* __restrict__ partial,
                               const float* __restrict__ maskx,
                               float* __restrict__ rowscale) {
    int idx = blockIdx.x * 256 + threadIdx.x;
    if (idx >= B * NX) return;
    float s = 0.f;
#pragma unroll
    for (int i = 0; i < NSPLIT; ++i) s += partial[(size_t)i * (B * NX) + idx];
    rowscale[idx] = maskx[idx] / s;
}

// ---------------- pass 2: LDS-staged GEMM + LDS-transpose epilogue ----------------
// MFMA phase identical to R4. Epilogue: scaled outputs round-trip through the
// (now dead) 64KB staging LDS laid out as tile[128x][512B] with x-XOR swizzle;
// store phase writes 2 complete 512B row-segments per wave instruction.
__global__ __launch_bounds__(256) void pass2_kernel(const __hip_bfloat16* __restrict__ Xn,
                                                    const __hip_bfloat16* __restrict__ Yn,
                                                    const float* __restrict__ rowscale,
                                                    const float* __restrict__ masky,
                                                    float* __restrict__ out) {
    __shared__ char smem[65536];
    char* XsB = smem;            // 32KB bf16 [128][128]
    char* YsB = smem + 32768;    // 32KB
    const int yt = blockIdx.x, xt = blockIdx.y, b = blockIdx.z;
    const int t = threadIdx.x;
    const int lane = t & 63, wid = t >> 6;
    const int wy = wid >> 1, wx = wid & 1;        // 2x2 waves, each 64y x 64x
    const int lrow = lane & 15, lhi = lane >> 4;

    stage_tile((const char*)(Xn + (size_t)(b * NX + xt * BM) * DD), XsB, wid, lane);
    stage_tile((const char*)(Yn + (size_t)(b * NY + yt * BN) * DD), YsB, wid, lane);
    __syncthreads();

    float4v acc[4][4];  // [n = y frag][m = x frag]
#pragma unroll
    for (int n = 0; n < 4; ++n)
#pragma unroll
        for (int m = 0; m < 4; ++m) acc[n][m] = (float4v)(0.f);

#pragma unroll
    for (int kk = 0; kk < 4; ++kk) {
        const int cb = (kk * 64 + lhi * 16) ^ ((lrow & 7) << 4);
        short8 a[4], bb[4];
#pragma unroll
        for (int n = 0; n < 4; ++n)
            a[n] = *(const short8*)(YsB + (size_t)(wy * 64 + n * 16 + lrow) * ROWB + cb);
#pragma unroll
        for (int m = 0; m < 4; ++m)
            bb[m] = *(const short8*)(XsB + (size_t)(wx * 64 + m * 16 + lrow) * ROWB + cb);
#pragma unroll
        for (int n = 0; n < 4; ++n)
#pragma unroll
            for (int m = 0; m < 4; ++m)
                acc[n][m] = __builtin_amdgcn_mfma_f32_16x16x32_bf16(a[n], bb[m], acc[n][m], 0, 0, 0);
    }

    const int ybase = yt * BN + wy * 64;
    const int xbase = xt * BM + wx * 64;

    float rs[4];
#pragma unroll
    for (int m = 0; m < 4; ++m)
        rs[m] = rowscale[(size_t)b * NX + xbase + m * 16 + lrow];
    float4v my4[4];
#pragma unroll
    for (int n = 0; n < 4; ++n)
        my4[n] = *(const float4v*)(masky + (size_t)b * NY + ybase + n * 16 + lhi * 4);

    __syncthreads();   // all waves done reading Xs/Ys; smem becomes out-tile

    // write phase: tile[x][ybytes ^ ((x&7)<<4)], x-row = 512B
#pragma unroll
    for (int m = 0; m < 4; ++m) {
        const int xl = wx * 64 + m * 16 + lrow;
#pragma unroll
        for (int n = 0; n < 4; ++n) {
            float4v o;
#pragma unroll
            for (int r = 0; r < 4; ++r)
                o[r] = __expf(acc[n][m][r] * TAU_INV) * rs[m] * my4[n][r];
            const int yb = wy * 256 + n * 64 + lhi * 16;   // byte offset in 512B row
            *(float4v*)(smem + (size_t)xl * 512 + (yb ^ ((xl & 7) << 4))) = o;
        }
    }
    __syncthreads();

    // store phase: each instruction = 2 complete 512B row-segments (full lines)
    const int halfl = lane >> 5, l31 = lane & 31;
    const size_t orow0 = ((size_t)b * NX + xt * BM) * NY + yt * BN;
#pragma unroll
    for (int s = 0; s < 16; ++s) {
        const int xr = wid * 32 + s * 2 + halfl;
        float4v v = *(const float4v*)(smem + (size_t)xr * 512 + ((l31 * 16) ^ ((xr & 7) << 4)));
        *(float4v*)(out + orow0 + (size_t)xr * NY + l31 * 4) = v;
    }
}

extern "C" void kernel_launch(void* const* d_in, const int* in_sizes, int n_in,
                              void* d_out, int out_size, void* d_ws, size_t ws_size,
                              hipStream_t stream) {
    const float* feat_x = (const float*)d_in[0];
    const float* feat_y = (const float*)d_in[1];
    const float* maskx  = (const float*)d_in[2];
    const float* masky  = (const float*)d_in[3];
    float* out = (float*)d_out;

    char* ws = (char*)d_ws;
    __hip_bfloat16* Xn = (__hip_bfloat16*)ws;                                   // 4 MB
    __hip_bfloat16* Yn = (__hip_bfloat16*)(ws + (size_t)B * NX * DD * 2);       // 4 MB
    float* partial  = (float*)(ws + (size_t)B * (NX + NY) * DD * 2);            // 512 KB
    float* rowscale = partial + (size_t)NSPLIT * B * NX;                        // 64 KB

    l2norm_kernel<<<B * NX / 4, 256, 0, stream>>>(feat_x, Xn, B * NX);
    l2norm_kernel<<<B * NY / 4, 256, 0, stream>>>(feat_y, Yn, B * NY);
    pass1_kernel<<<dim3(NSPLIT, NX / BM, B), 256, 0, stream>>>(Xn, Yn, partial);
    combine_kernel<<<(B * NX + 255) / 256, 256, 0, stream>>>(partial, maskx, rowscale);
    pass2_kernel<<<dim3(NY / BN, NX / BM, B), 256, 0, stream>>>(Xn, Yn, rowscale, masky, out);
}